// Round 3
// baseline (2489.824 us; speedup 1.0000x reference)
//
#include <hip/hip_runtime.h>
#include <cstdint>
#include <cstddef>

// ============================================================================
// ConditionalRBM sampler — bit-exact resimulation of the JAX reference.
//
// Round-3 post-mortem: compiler SCALARIZED the block-uniform state loads
// (VGPR=24, s_load + lgkmcnt(0) drain per iter -> serial latency chain).
// Round-4: stage state tile (256k x 4 rows = 4KiB) in LDS ONCE (single
// barrier), then a barrier-free 256-k loop: 1 coalesced global w-load +
// 1 uniform ds_read_b128 (broadcast, conflict-free) + 4 fma per k.
// RT=4 -> 2048 blocks = 8 blocks/CU = 8 waves/SIMD (launch_bounds(256,8),
// register-lean loop stays under the 64-VGPR occupancy cliff).
// Accumulation order per output unchanged: single ascending-k fma chain.
//
// ASSUMPTION STACK (verified bit-exact in earlier rounds):
//  A1: jax_threefry_partitionable = True:
//      split(key,n)[i] = TF(key,(0,i)); bits32[j] = TF0(key,(0,j)) ^ TF1(key,(0,j))
//  A2: logistic(x) = 1/(1+exp(-x)), IEEE fdiv
//  A3: exp = XLA-CPU vectorized Cephes/Eigen pexp
//  A4: dot = ascending-k single-accumulator fma chain (exact 0/1 products)
//  A5: x = (dot + udot) + bias association
//  Output dtype: int32 0/1 (harness reads d_out as int32).
// ============================================================================

#pragma clang fp contract(off)

#define BATCH 8192
#define NU 64
#define NF 256   // num_v == num_h == 256
#define RT 4     // rows per thread in k_phase (grid = 2048 blocks)
#define RTI 16   // rows per block in k_init / k_udot
#define THERM 24
#define NSAMP 8

// ---------------- Threefry-2x32 (JAX rotation/injection schedule) ----------
__host__ __device__ __forceinline__ void tf2x32(uint32_t k0, uint32_t k1,
                                                uint32_t x0, uint32_t x1,
                                                uint32_t* o0, uint32_t* o1) {
  uint32_t ks2 = k0 ^ k1 ^ 0x1BD11BDAu;
  x0 += k0; x1 += k1;
#define TFR(r) { x0 += x1; x1 = (x1 << (r)) | (x1 >> (32 - (r))); x1 ^= x0; }
  TFR(13) TFR(15) TFR(26) TFR(6)
  x0 += k1;  x1 += ks2 + 1u;
  TFR(17) TFR(29) TFR(16) TFR(24)
  x0 += ks2; x1 += k0 + 2u;
  TFR(13) TFR(15) TFR(26) TFR(6)
  x0 += k0;  x1 += k1 + 3u;
  TFR(17) TFR(29) TFR(16) TFR(24)
  x0 += k1;  x1 += ks2 + 4u;
  TFR(13) TFR(15) TFR(26) TFR(6)
  x0 += ks2; x1 += k0 + 5u;
#undef TFR
  *o0 = x0; *o1 = x1;
}

// ---------------- XLA-CPU expf (Cephes/Eigen polynomial) -------------------
__device__ __forceinline__ float xla_expf(float x) {
  float xc = fminf(x, 88.3762626647950f);
  xc = fmaxf(xc, -88.3762626647949f);
  float fx = floorf(__builtin_fmaf(xc, 1.44269504088896341f, 0.5f));
  float tmp = 0.693359375f * fx;          // separate rounding (contract off)
  float z = -2.12194440e-4f * fx;
  float r = xc - tmp;
  r = r - z;
  z = r * r;
  float y = __builtin_fmaf(r, 1.9875691500e-4f, 1.3981999507e-3f);
  y = __builtin_fmaf(y, r, 8.3334519073e-3f);
  y = __builtin_fmaf(y, r, 4.1665795894e-2f);
  y = __builtin_fmaf(y, r, 1.6666665459e-1f);
  y = __builtin_fmaf(y, r, 5.0000001201e-1f);
  y = __builtin_fmaf(y, z, r);
  y = y + 1.0f;
  int n = (int)fx;
  float p2 = __int_as_float((n + 127) << 23);
  float res = y * p2;
  return fmaxf(res, x);                   // Eigen pexp: pmax(res, original x)
}

__device__ __forceinline__ float sigmoid_ref(float x) {
  float e = xla_expf(-x);                 // negate exact
  return 1.0f / (1.0f + e);               // IEEE fdiv (no fast-math)
}

// bern: partitionable threefry bits -> uniform [0,1) -> (u < p)
__device__ __forceinline__ float bern_sample(uint32_t key0, uint32_t key1,
                                             uint32_t idx, float p) {
  uint32_t b0, b1;
  tf2x32(key0, key1, 0u, idx, &b0, &b1);  // counter = (hi=0, lo=flat_idx)
  uint32_t bits = b0 ^ b1;                // 32-bit path XORs both words
  float u = __uint_as_float((bits >> 9) | 0x3f800000u) - 1.0f;
  return (u < p) ? 1.0f : 0.0f;
}

// ---------------- kernels ---------------------------------------------------
__global__ void k_transpose(const float* __restrict__ Whv,
                            float* __restrict__ WhvT) {
  int j = threadIdx.x;  // hidden
  int k = blockIdx.x;   // visible
  WhvT[k * NF + j] = Whv[j * NF + k];
}

// out[row][j] = sum_k u[row][k] * W[j][k], ascending k (exact products).
// W row j lives in registers; u-chunk (RTI rows x 64) broadcast from LDS.
__global__ __launch_bounds__(256, 2) void k_udot(const float* __restrict__ U,
                                                 const float* __restrict__ W,
                                                 float* __restrict__ out) {
  __shared__ __align__(16) float Ulds[NU * RTI];  // [k][i], 4 KiB
  const int j = threadIdx.x;
  const int i0 = blockIdx.x * RTI;
  const int si = j & 15;          // row within tile
  const int sg = j >> 4;          // 4-col group (16 groups cover 64 cols)
  {
    float4 u4 = *(const float4*)(U + (size_t)(i0 + si) * NU + sg * 4);
    Ulds[(sg * 4 + 0) * RTI + si] = u4.x;
    Ulds[(sg * 4 + 1) * RTI + si] = u4.y;
    Ulds[(sg * 4 + 2) * RTI + si] = u4.z;
    Ulds[(sg * 4 + 3) * RTI + si] = u4.w;
  }
  float wreg[NU];
  const float4* wr4 = (const float4*)(W + (size_t)j * NU);
#pragma unroll
  for (int r = 0; r < NU / 4; ++r) {
    float4 t = wr4[r];
    wreg[4 * r + 0] = t.x; wreg[4 * r + 1] = t.y;
    wreg[4 * r + 2] = t.z; wreg[4 * r + 3] = t.w;
  }
  __syncthreads();
  float acc[RTI];
#pragma unroll
  for (int i = 0; i < RTI; ++i) acc[i] = 0.0f;
#pragma unroll
  for (int kk = 0; kk < NU; ++kk) {
    const float w = wreg[kk];
    const float4 s0 = *(const float4*)(&Ulds[kk * RTI + 0]);
    const float4 s1 = *(const float4*)(&Ulds[kk * RTI + 4]);
    const float4 s2 = *(const float4*)(&Ulds[kk * RTI + 8]);
    const float4 s3 = *(const float4*)(&Ulds[kk * RTI + 12]);
    acc[0]  = __builtin_fmaf(s0.x, w, acc[0]);
    acc[1]  = __builtin_fmaf(s0.y, w, acc[1]);
    acc[2]  = __builtin_fmaf(s0.z, w, acc[2]);
    acc[3]  = __builtin_fmaf(s0.w, w, acc[3]);
    acc[4]  = __builtin_fmaf(s1.x, w, acc[4]);
    acc[5]  = __builtin_fmaf(s1.y, w, acc[5]);
    acc[6]  = __builtin_fmaf(s1.z, w, acc[6]);
    acc[7]  = __builtin_fmaf(s1.w, w, acc[7]);
    acc[8]  = __builtin_fmaf(s2.x, w, acc[8]);
    acc[9]  = __builtin_fmaf(s2.y, w, acc[9]);
    acc[10] = __builtin_fmaf(s2.z, w, acc[10]);
    acc[11] = __builtin_fmaf(s2.w, w, acc[11]);
    acc[12] = __builtin_fmaf(s3.x, w, acc[12]);
    acc[13] = __builtin_fmaf(s3.y, w, acc[13]);
    acc[14] = __builtin_fmaf(s3.z, w, acc[14]);
    acc[15] = __builtin_fmaf(s3.w, w, acc[15]);
  }
#pragma unroll
  for (int i = 0; i < RTI; ++i)
    out[(size_t)(i0 + i) * NF + j] = acc[i];   // row-major C (coalesced)
}

// v0 = bern(ks[0], sigmoid(uv + bv)); writes transposed state Vt[j][row]
__global__ __launch_bounds__(256) void k_init(const float* __restrict__ uv,
                                              const float* __restrict__ bv,
                                              float* __restrict__ Vt,
                                              uint32_t key0, uint32_t key1) {
  int j = threadIdx.x;
  int i0 = blockIdx.x * RTI;
  float b = bv[j];
  float vals[RTI];
#pragma unroll
  for (int i = 0; i < RTI; ++i) {
    int row = i0 + i;
    uint32_t idx = (uint32_t)(row * NF + j);
    float x = uv[idx] + b;                // (dot) + bias : single add
    float p = sigmoid_ref(x);
    vals[i] = bern_sample(key0, key1, idx, p);
  }
  float4* dst = (float4*)(Vt + (size_t)j * BATCH + i0);
#pragma unroll
  for (int q = 0; q < RTI / 4; ++q)
    dst[q] = make_float4(vals[4 * q], vals[4 * q + 1], vals[4 * q + 2], vals[4 * q + 3]);
}

// One Gibbs half-step: O = bern(key, sigmoid((St^T @ W) + C + bias))
// St: prev state transposed [256 k][8192 i]; W: [256 k][256 j] k-major;
// C: u-dot row-major [8192][256]; Ot: next state transposed; smp: int32 out.
// State tile (256k x RT rows = 4KiB) staged in LDS once (1 barrier), then a
// barrier-free k-loop: coalesced global w-load + uniform ds_read_b128
// (broadcast) + RT fmas per k. 2048 blocks -> 8 blocks/CU -> 8 waves/SIMD.
__global__ __launch_bounds__(256, 8) void k_phase(const float* __restrict__ St,
                                                  const float* __restrict__ W,
                                                  const float* __restrict__ C,
                                                  const float* __restrict__ bias,
                                                  float* __restrict__ Ot,
                                                  int* __restrict__ smp,
                                                  uint32_t key0, uint32_t key1) {
  __shared__ __align__(16) float Slds[NF * RT];   // [k][i], 4 KiB
  const int j = threadIdx.x;
  const int i0 = blockIdx.x * RT;

  // stage: thread t copies state row k=t (RT floats, one b128)
  ((float4*)Slds)[j] = *(const float4*)(St + (size_t)j * BATCH + i0);
  __syncthreads();

  float acc[RT];
#pragma unroll
  for (int i = 0; i < RT; ++i) acc[i] = 0.0f;

  const float* pw = W + j;        // column j of W, stride NF
#pragma unroll 8
  for (int k = 0; k < NF; ++k) {
    const float w = pw[(size_t)k * NF];                  // coalesced, L1-hot
    const float4 s = *(const float4*)(&Slds[k * RT]);    // uniform broadcast
    acc[0] = __builtin_fmaf(s.x, w, acc[0]);   // exact product (0/1)
    acc[1] = __builtin_fmaf(s.y, w, acc[1]);
    acc[2] = __builtin_fmaf(s.z, w, acc[2]);
    acc[3] = __builtin_fmaf(s.w, w, acc[3]);
  }

  const float b = bias[j];
  float vals[RT];
#pragma unroll
  for (int i = 0; i < RT; ++i) {
    int row = i0 + i;
    uint32_t idx = (uint32_t)(row * NF + j);
    float x = (acc[i] + C[idx]) + b;      // (dot + udot) + bias
    float p = sigmoid_ref(x);
    vals[i] = bern_sample(key0, key1, idx, p);
  }
  *(float4*)(Ot + (size_t)j * BATCH + i0) =
      make_float4(vals[0], vals[1], vals[2], vals[3]);
  if (smp) {
#pragma unroll
    for (int i = 0; i < RT; ++i)
      smp[(size_t)(i0 + i) * NF + j] = (vals[i] != 0.0f) ? 1 : 0;  // int32
  }
}

// ---------------- launch ----------------------------------------------------
extern "C" void kernel_launch(void* const* d_in, const int* in_sizes, int n_in,
                              void* d_out, int out_size, void* d_ws, size_t ws_size,
                              hipStream_t stream) {
  const float* u_state = (const float*)d_in[0];  // [8192][64] 0/1 floats
  const float* Wvu     = (const float*)d_in[1];  // [256][64]
  const float* Whu     = (const float*)d_in[2];  // [256][64]
  const float* Whv     = (const float*)d_in[3];  // [256][256]
  const float* bv      = (const float*)d_in[4];  // [256]
  const float* bh      = (const float*)d_in[5];  // [256]
  int* out = (int*)d_out;                        // [8][8192][256] as int32 0/1

  // workspace layout (floats); total 8,454,144 f32 = 33.8 MB
  float* ws   = (float*)d_ws;
  float* WhvT = ws;                        // 65536
  float* uh   = WhvT + NF * NF;            // row-major [8192][256]
  float* uv   = uh + (size_t)BATCH * NF;
  float* Vt   = uv + (size_t)BATCH * NF;   // state, transposed [256][8192]
  float* Ht   = Vt + (size_t)BATCH * NF;

  // ---- host-side key schedule (pure CPU, deterministic) ----
  uint32_t s0[THERM + NSAMP + 1], s1[THERM + NSAMP + 1];
  for (uint32_t i = 0; i < THERM + NSAMP + 1; ++i)
    tf2x32(0u, 1u, 0u, i, &s0[i], &s1[i]);

  k_transpose<<<NF, NF, 0, stream>>>(Whv, WhvT);
  k_udot<<<BATCH / RTI, NF, 0, stream>>>(u_state, Whu, uh);   // u @ Whu.T
  k_udot<<<BATCH / RTI, NF, 0, stream>>>(u_state, Wvu, uv);   // u @ Wvu.T
  k_init<<<BATCH / RTI, NF, 0, stream>>>(uv, bv, Vt, s0[0], s1[0]);

  for (int t = 0; t < THERM + NSAMP; ++t) {
    uint32_t kh0, kh1, kv0, kv1;
    tf2x32(s0[1 + t], s1[1 + t], 0u, 0u, &kh0, &kh1);
    tf2x32(s0[1 + t], s1[1 + t], 0u, 1u, &kv0, &kv1);
    int* smp = (t >= THERM) ? out + (size_t)(t - THERM) * BATCH * NF : (int*)nullptr;
    // h = bern(k1, sigmoid(v @ Whv.T + uh + bh))
    k_phase<<<BATCH / RT, NF, 0, stream>>>(Vt, WhvT, uh, bh, Ht, (int*)nullptr, kh0, kh1);
    // v = bern(k2, sigmoid(h @ Whv + uv + bv)) ; emit sample when t>=THERM
    k_phase<<<BATCH / RT, NF, 0, stream>>>(Ht, Whv, uv, bv, Vt, smp, kv0, kv1);
  }
  (void)in_sizes; (void)n_in; (void)out_size; (void)ws_size;
}

// Round 4
// 1969.149 us; speedup vs baseline: 1.2644x; 1.2644x over previous
//
#include <hip/hip_runtime.h>
#include <cstdint>
#include <cstddef>

// ============================================================================
// ConditionalRBM sampler — bit-exact resimulation of the JAX reference.
//
// Round-4 post-mortem: RT=4 doubled the W L2 stream (2048 blocks x 256KB =
// 512MB/phase ~ 15us floor) and launch_bounds(256,8)'s 64-VGPR cap almost
// certainly spilled the threefry epilogue -> no net win (38.6us/phase).
// Round-5: keep the LDS-state skeleton; RT=8 (W traffic halved to 256MB,
// 8 fma per {1 w-load + 2 uniform LDS b128}), launch_bounds(256,4) = 128
// VGPR budget (no spill), 4 blocks/CU x 8KiB LDS = 4 waves/SIMD, unroll 16
// for 16 in-flight w-loads.
// Accumulation order per output unchanged: single ascending-k fma chain.
//
// ASSUMPTION STACK (verified bit-exact in earlier rounds):
//  A1: jax_threefry_partitionable = True:
//      split(key,n)[i] = TF(key,(0,i)); bits32[j] = TF0(key,(0,j)) ^ TF1(key,(0,j))
//  A2: logistic(x) = 1/(1+exp(-x)), IEEE fdiv
//  A3: exp = XLA-CPU vectorized Cephes/Eigen pexp
//  A4: dot = ascending-k single-accumulator fma chain (exact 0/1 products)
//  A5: x = (dot + udot) + bias association
//  Output dtype: int32 0/1 (harness reads d_out as int32).
// ============================================================================

#pragma clang fp contract(off)

#define BATCH 8192
#define NU 64
#define NF 256   // num_v == num_h == 256
#define RT 8     // rows per block in k_phase (grid = 1024 blocks)
#define RTI 16   // rows per block in k_init / k_udot
#define THERM 24
#define NSAMP 8

// ---------------- Threefry-2x32 (JAX rotation/injection schedule) ----------
__host__ __device__ __forceinline__ void tf2x32(uint32_t k0, uint32_t k1,
                                                uint32_t x0, uint32_t x1,
                                                uint32_t* o0, uint32_t* o1) {
  uint32_t ks2 = k0 ^ k1 ^ 0x1BD11BDAu;
  x0 += k0; x1 += k1;
#define TFR(r) { x0 += x1; x1 = (x1 << (r)) | (x1 >> (32 - (r))); x1 ^= x0; }
  TFR(13) TFR(15) TFR(26) TFR(6)
  x0 += k1;  x1 += ks2 + 1u;
  TFR(17) TFR(29) TFR(16) TFR(24)
  x0 += ks2; x1 += k0 + 2u;
  TFR(13) TFR(15) TFR(26) TFR(6)
  x0 += k0;  x1 += k1 + 3u;
  TFR(17) TFR(29) TFR(16) TFR(24)
  x0 += k1;  x1 += ks2 + 4u;
  TFR(13) TFR(15) TFR(26) TFR(6)
  x0 += ks2; x1 += k0 + 5u;
#undef TFR
  *o0 = x0; *o1 = x1;
}

// ---------------- XLA-CPU expf (Cephes/Eigen polynomial) -------------------
__device__ __forceinline__ float xla_expf(float x) {
  float xc = fminf(x, 88.3762626647950f);
  xc = fmaxf(xc, -88.3762626647949f);
  float fx = floorf(__builtin_fmaf(xc, 1.44269504088896341f, 0.5f));
  float tmp = 0.693359375f * fx;          // separate rounding (contract off)
  float z = -2.12194440e-4f * fx;
  float r = xc - tmp;
  r = r - z;
  z = r * r;
  float y = __builtin_fmaf(r, 1.9875691500e-4f, 1.3981999507e-3f);
  y = __builtin_fmaf(y, r, 8.3334519073e-3f);
  y = __builtin_fmaf(y, r, 4.1665795894e-2f);
  y = __builtin_fmaf(y, r, 1.6666665459e-1f);
  y = __builtin_fmaf(y, r, 5.0000001201e-1f);
  y = __builtin_fmaf(y, z, r);
  y = y + 1.0f;
  int n = (int)fx;
  float p2 = __int_as_float((n + 127) << 23);
  float res = y * p2;
  return fmaxf(res, x);                   // Eigen pexp: pmax(res, original x)
}

__device__ __forceinline__ float sigmoid_ref(float x) {
  float e = xla_expf(-x);                 // negate exact
  return 1.0f / (1.0f + e);               // IEEE fdiv (no fast-math)
}

// bern: partitionable threefry bits -> uniform [0,1) -> (u < p)
__device__ __forceinline__ float bern_sample(uint32_t key0, uint32_t key1,
                                             uint32_t idx, float p) {
  uint32_t b0, b1;
  tf2x32(key0, key1, 0u, idx, &b0, &b1);  // counter = (hi=0, lo=flat_idx)
  uint32_t bits = b0 ^ b1;                // 32-bit path XORs both words
  float u = __uint_as_float((bits >> 9) | 0x3f800000u) - 1.0f;
  return (u < p) ? 1.0f : 0.0f;
}

// ---------------- kernels ---------------------------------------------------
__global__ void k_transpose(const float* __restrict__ Whv,
                            float* __restrict__ WhvT) {
  int j = threadIdx.x;  // hidden
  int k = blockIdx.x;   // visible
  WhvT[k * NF + j] = Whv[j * NF + k];
}

// out[row][j] = sum_k u[row][k] * W[j][k], ascending k (exact products).
// W row j lives in registers; u-chunk (RTI rows x 64) broadcast from LDS.
__global__ __launch_bounds__(256, 2) void k_udot(const float* __restrict__ U,
                                                 const float* __restrict__ W,
                                                 float* __restrict__ out) {
  __shared__ __align__(16) float Ulds[NU * RTI];  // [k][i], 4 KiB
  const int j = threadIdx.x;
  const int i0 = blockIdx.x * RTI;
  const int si = j & 15;          // row within tile
  const int sg = j >> 4;          // 4-col group (16 groups cover 64 cols)
  {
    float4 u4 = *(const float4*)(U + (size_t)(i0 + si) * NU + sg * 4);
    Ulds[(sg * 4 + 0) * RTI + si] = u4.x;
    Ulds[(sg * 4 + 1) * RTI + si] = u4.y;
    Ulds[(sg * 4 + 2) * RTI + si] = u4.z;
    Ulds[(sg * 4 + 3) * RTI + si] = u4.w;
  }
  float wreg[NU];
  const float4* wr4 = (const float4*)(W + (size_t)j * NU);
#pragma unroll
  for (int r = 0; r < NU / 4; ++r) {
    float4 t = wr4[r];
    wreg[4 * r + 0] = t.x; wreg[4 * r + 1] = t.y;
    wreg[4 * r + 2] = t.z; wreg[4 * r + 3] = t.w;
  }
  __syncthreads();
  float acc[RTI];
#pragma unroll
  for (int i = 0; i < RTI; ++i) acc[i] = 0.0f;
#pragma unroll
  for (int kk = 0; kk < NU; ++kk) {
    const float w = wreg[kk];
    const float4 s0 = *(const float4*)(&Ulds[kk * RTI + 0]);
    const float4 s1 = *(const float4*)(&Ulds[kk * RTI + 4]);
    const float4 s2 = *(const float4*)(&Ulds[kk * RTI + 8]);
    const float4 s3 = *(const float4*)(&Ulds[kk * RTI + 12]);
    acc[0]  = __builtin_fmaf(s0.x, w, acc[0]);
    acc[1]  = __builtin_fmaf(s0.y, w, acc[1]);
    acc[2]  = __builtin_fmaf(s0.z, w, acc[2]);
    acc[3]  = __builtin_fmaf(s0.w, w, acc[3]);
    acc[4]  = __builtin_fmaf(s1.x, w, acc[4]);
    acc[5]  = __builtin_fmaf(s1.y, w, acc[5]);
    acc[6]  = __builtin_fmaf(s1.z, w, acc[6]);
    acc[7]  = __builtin_fmaf(s1.w, w, acc[7]);
    acc[8]  = __builtin_fmaf(s2.x, w, acc[8]);
    acc[9]  = __builtin_fmaf(s2.y, w, acc[9]);
    acc[10] = __builtin_fmaf(s2.z, w, acc[10]);
    acc[11] = __builtin_fmaf(s2.w, w, acc[11]);
    acc[12] = __builtin_fmaf(s3.x, w, acc[12]);
    acc[13] = __builtin_fmaf(s3.y, w, acc[13]);
    acc[14] = __builtin_fmaf(s3.z, w, acc[14]);
    acc[15] = __builtin_fmaf(s3.w, w, acc[15]);
  }
#pragma unroll
  for (int i = 0; i < RTI; ++i)
    out[(size_t)(i0 + i) * NF + j] = acc[i];   // row-major C (coalesced)
}

// v0 = bern(ks[0], sigmoid(uv + bv)); writes transposed state Vt[j][row]
__global__ __launch_bounds__(256) void k_init(const float* __restrict__ uv,
                                              const float* __restrict__ bv,
                                              float* __restrict__ Vt,
                                              uint32_t key0, uint32_t key1) {
  int j = threadIdx.x;
  int i0 = blockIdx.x * RTI;
  float b = bv[j];
  float vals[RTI];
#pragma unroll
  for (int i = 0; i < RTI; ++i) {
    int row = i0 + i;
    uint32_t idx = (uint32_t)(row * NF + j);
    float x = uv[idx] + b;                // (dot) + bias : single add
    float p = sigmoid_ref(x);
    vals[i] = bern_sample(key0, key1, idx, p);
  }
  float4* dst = (float4*)(Vt + (size_t)j * BATCH + i0);
#pragma unroll
  for (int q = 0; q < RTI / 4; ++q)
    dst[q] = make_float4(vals[4 * q], vals[4 * q + 1], vals[4 * q + 2], vals[4 * q + 3]);
}

// One Gibbs half-step: O = bern(key, sigmoid((St^T @ W) + C + bias))
// St: prev state transposed [256 k][8192 i]; W: [256 k][256 j] k-major;
// C: u-dot row-major [8192][256]; Ot: next state transposed; smp: int32 out.
// State tile (256k x RT=8 rows = 8KiB) staged in LDS once (1 barrier), then
// a barrier-free k-loop: coalesced global w-load + 2 uniform ds_read_b128
// (broadcast) + 8 fmas per k. 1024 blocks, 4 blocks/CU, 4 waves/SIMD.
__global__ __launch_bounds__(256, 4) void k_phase(const float* __restrict__ St,
                                                  const float* __restrict__ W,
                                                  const float* __restrict__ C,
                                                  const float* __restrict__ bias,
                                                  float* __restrict__ Ot,
                                                  int* __restrict__ smp,
                                                  uint32_t key0, uint32_t key1) {
  __shared__ __align__(16) float Slds[NF * RT];   // [k][i], 8 KiB
  const int j = threadIdx.x;
  const int i0 = blockIdx.x * RT;

  // stage: thread t copies state row k=t (RT floats = 2 x b128, contiguous)
  {
    const float* src = St + (size_t)j * BATCH + i0;
    ((float4*)Slds)[2 * j + 0] = *(const float4*)(src);
    ((float4*)Slds)[2 * j + 1] = *(const float4*)(src + 4);
  }
  __syncthreads();

  float acc[RT];
#pragma unroll
  for (int i = 0; i < RT; ++i) acc[i] = 0.0f;

  const float* pw = W + j;        // column j of W, stride NF
#pragma unroll 16
  for (int k = 0; k < NF; ++k) {
    const float w = pw[(size_t)k * NF];                    // coalesced, L2-hot
    const float4 sA = *(const float4*)(&Slds[k * RT + 0]); // uniform broadcast
    const float4 sB = *(const float4*)(&Slds[k * RT + 4]); // uniform broadcast
    acc[0] = __builtin_fmaf(sA.x, w, acc[0]);   // exact product (0/1)
    acc[1] = __builtin_fmaf(sA.y, w, acc[1]);
    acc[2] = __builtin_fmaf(sA.z, w, acc[2]);
    acc[3] = __builtin_fmaf(sA.w, w, acc[3]);
    acc[4] = __builtin_fmaf(sB.x, w, acc[4]);
    acc[5] = __builtin_fmaf(sB.y, w, acc[5]);
    acc[6] = __builtin_fmaf(sB.z, w, acc[6]);
    acc[7] = __builtin_fmaf(sB.w, w, acc[7]);
  }

  const float b = bias[j];
  float vals[RT];
#pragma unroll
  for (int i = 0; i < RT; ++i) {
    int row = i0 + i;
    uint32_t idx = (uint32_t)(row * NF + j);
    float x = (acc[i] + C[idx]) + b;      // (dot + udot) + bias
    float p = sigmoid_ref(x);
    vals[i] = bern_sample(key0, key1, idx, p);
  }
  float4* dst = (float4*)(Ot + (size_t)j * BATCH + i0);
  dst[0] = make_float4(vals[0], vals[1], vals[2], vals[3]);
  dst[1] = make_float4(vals[4], vals[5], vals[6], vals[7]);
  if (smp) {
#pragma unroll
    for (int i = 0; i < RT; ++i)
      smp[(size_t)(i0 + i) * NF + j] = (vals[i] != 0.0f) ? 1 : 0;  // int32
  }
}

// ---------------- launch ----------------------------------------------------
extern "C" void kernel_launch(void* const* d_in, const int* in_sizes, int n_in,
                              void* d_out, int out_size, void* d_ws, size_t ws_size,
                              hipStream_t stream) {
  const float* u_state = (const float*)d_in[0];  // [8192][64] 0/1 floats
  const float* Wvu     = (const float*)d_in[1];  // [256][64]
  const float* Whu     = (const float*)d_in[2];  // [256][64]
  const float* Whv     = (const float*)d_in[3];  // [256][256]
  const float* bv      = (const float*)d_in[4];  // [256]
  const float* bh      = (const float*)d_in[5];  // [256]
  int* out = (int*)d_out;                        // [8][8192][256] as int32 0/1

  // workspace layout (floats); total 8,454,144 f32 = 33.8 MB
  float* ws   = (float*)d_ws;
  float* WhvT = ws;                        // 65536
  float* uh   = WhvT + NF * NF;            // row-major [8192][256]
  float* uv   = uh + (size_t)BATCH * NF;
  float* Vt   = uv + (size_t)BATCH * NF;   // state, transposed [256][8192]
  float* Ht   = Vt + (size_t)BATCH * NF;

  // ---- host-side key schedule (pure CPU, deterministic) ----
  uint32_t s0[THERM + NSAMP + 1], s1[THERM + NSAMP + 1];
  for (uint32_t i = 0; i < THERM + NSAMP + 1; ++i)
    tf2x32(0u, 1u, 0u, i, &s0[i], &s1[i]);

  k_transpose<<<NF, NF, 0, stream>>>(Whv, WhvT);
  k_udot<<<BATCH / RTI, NF, 0, stream>>>(u_state, Whu, uh);   // u @ Whu.T
  k_udot<<<BATCH / RTI, NF, 0, stream>>>(u_state, Wvu, uv);   // u @ Wvu.T
  k_init<<<BATCH / RTI, NF, 0, stream>>>(uv, bv, Vt, s0[0], s1[0]);

  for (int t = 0; t < THERM + NSAMP; ++t) {
    uint32_t kh0, kh1, kv0, kv1;
    tf2x32(s0[1 + t], s1[1 + t], 0u, 0u, &kh0, &kh1);
    tf2x32(s0[1 + t], s1[1 + t], 0u, 1u, &kv0, &kv1);
    int* smp = (t >= THERM) ? out + (size_t)(t - THERM) * BATCH * NF : (int*)nullptr;
    // h = bern(k1, sigmoid(v @ Whv.T + uh + bh))
    k_phase<<<BATCH / RT, NF, 0, stream>>>(Vt, WhvT, uh, bh, Ht, (int*)nullptr, kh0, kh1);
    // v = bern(k2, sigmoid(h @ Whv + uv + bv)) ; emit sample when t>=THERM
    k_phase<<<BATCH / RT, NF, 0, stream>>>(Ht, Whv, uv, bv, Vt, smp, kv0, kv1);
  }
  (void)in_sizes; (void)n_in; (void)out_size; (void)ws_size;
}